// Round 11
// baseline (133.142 us; speedup 1.0000x reference)
//
#include <hip/hip_runtime.h>

typedef unsigned long long ull;

#define NANCH   131072
#define NMAX    64
#define NBATCH  16
#define THREADS 256

// ---------------------------------------------------------------------------
// Sorted-path ws layout (bytes):
//   0        ull cells[1024]        packed per-(batch,gt) argmax
//   8192     double partials[1024]
//   16384    int chunkH[256][256]   chunk histograms -> (in-place) bases
//   278528   int cellid[NANCH]
//   802816   float4 sorted[NANCH]
//   2899968  int sidx[NANCH]
//   3424256  = WS_NEED
// Fallback (R10) ws layout: cells@0, partials@8192, pairs@16384,
//   lanepk@16448, nbund@20544.
// cells packed as (r_bits<<32)|(0x7FFFFFFF-idx), r = inter/(areaA+areaB),
// a monotone bijection of iou, >= 0 -> float bits unsigned-monotonic; ties ->
// larger low word -> smaller ORIGINAL anchor index == JAX argmax semantics.
// Init 0x7FFFFFFF == pack(0, idx 0): if no anchor overlaps a gt, argmax = 0,
// exactly matching argmax over an all-zero iou column.
// ---------------------------------------------------------------------------
#define OFF_PART  8192
#define OFF_CH    16384
#define OFF_CID   278528
#define OFF_SRT   802816
#define OFF_SIX   2899968
#define WS_NEED   3424256
#define OFF_PAIRS 16384
#define OFF_LANE  16448
#define OFF_NB    20544

__device__ __forceinline__ float focal_f(float p) {
    float om = 1.0f - p;
    return -om * om * __logf(p);
}

// ========================= sorted path: sort stage =========================
__global__ __launch_bounds__(256) void k_hist(
    const float* __restrict__ anchors, int* __restrict__ cellid,
    int* __restrict__ chunkH)
{
    __shared__ int h[256];
    int tid = threadIdx.x, c = blockIdx.x;
    h[tid] = 0; __syncthreads();
    #pragma unroll
    for (int k = 0; k < 2; ++k) {
        int i = c*512 + tid + k*256;
        float4 v = reinterpret_cast<const float4*>(anchors)[i];
        int cx = (int)(v.x * 20.0f); cx = cx < 0 ? 0 : (cx > 15 ? 15 : cx);
        int cy = (int)(v.y * 20.0f); cy = cy < 0 ? 0 : (cy > 15 ? 15 : cy);
        int cell = cy*16 + cx;
        cellid[i] = cell;
        atomicAdd(&h[cell], 1);
    }
    __syncthreads();
    chunkH[c*256 + tid] = h[tid];
}

__global__ __launch_bounds__(256) void k_scan(
    int* __restrict__ CH, ull* __restrict__ cells)
{
    __shared__ int total[256];
    __shared__ int cstart[256];
    int b = threadIdx.x;
    int run = 0;
    for (int c = 0; c < 256; ++c) { int h = CH[c*256+b]; CH[c*256+b] = run; run += h; }
    total[b] = run;
    __syncthreads();
    if (b == 0) { int cs = 0; for (int i = 0; i < 256; ++i) { cstart[i] = cs; cs += total[i]; } }
    __syncthreads();
    int s = cstart[b];
    for (int c = 0; c < 256; ++c) CH[c*256+b] += s;
    for (int i = b; i < NBATCH*NMAX; i += 256) cells[i] = 0x7FFFFFFFull;
}

__global__ __launch_bounds__(256) void k_scatter(
    const float* __restrict__ anchors, const int* __restrict__ cellid,
    const int* __restrict__ CB, float4* __restrict__ sorted,
    int* __restrict__ sidx)
{
    __shared__ int lc[512];
    int tid = threadIdx.x, c = blockIdx.x;
    lc[tid]     = cellid[c*512 + tid];
    lc[tid+256] = cellid[c*512 + 256 + tid];
    __syncthreads();
    int i0 = 2*tid, i1 = 2*tid + 1;
    int c0 = lc[i0], c1 = lc[i1];
    int r0 = 0, r1 = 0;
    for (int j = 0; j < i0; ++j) { int cj = lc[j]; r0 += (cj==c0)?1:0; r1 += (cj==c1)?1:0; }
    r1 += (c0 == c1) ? 1 : 0;
    int g0 = c*512 + i0, g1 = c*512 + i1;
    int p0 = CB[c*256 + c0] + r0, p1 = CB[c*256 + c1] + r1;
    sorted[p0] = reinterpret_cast<const float4*>(anchors)[g0]; sidx[p0] = g0;
    sorted[p1] = reinterpret_cast<const float4*>(anchors)[g1]; sidx[p1] = g1;
}

// ================== sorted path: fused main (2 roles) ======================
// even bid -> role A: wave owns 256 spatially-sorted anchors; per (batch,gt)
//   wave-uniform bbox skip; survivors get IoU once -> count + packed argmax.
//   Epilogue adds sparse positive deltas vs background focal.
// odd bid  -> role B: coalesced streaming background focal over all classes.
__global__ __launch_bounds__(THREADS) void k_main_s(
    const float* __restrict__ thr_p,
    const float* __restrict__ classes,
    const float4* __restrict__ sorted,
    const int*   __restrict__ sidx,
    const float* __restrict__ gt,
    const int*   __restrict__ nobj,
    ull* __restrict__ cells,
    double* __restrict__ partials)
{
    int bid = blockIdx.x, tid = threadIdx.x;
    int wv = tid >> 6, ln = tid & 63;
    float thr = *thr_p;
    float q   = thr / (1.0f + thr);      // iou>thr <=> inter > q*aarea + q*garea
    __shared__ double sw[4];
    double acc = 0.0;

    if ((bid & 1) == 0) {
        // ---------------- role A ----------------
        int aid  = bid >> 1;             // 0..511
        int sblk = aid >> 2, bg = aid & 3;
        __shared__ float4 sgt[4*64];     // gt xyxy
        __shared__ float2 sgq[4*64];     // {q*garea, garea}
        __shared__ int    snobj[4];
        {
            int bb = tid >> 6, n = tid & 63;
            int b = bg + 4*bb;
            float4 g = reinterpret_cast<const float4*>(gt)[b*NMAX + n];
            float x2 = g.x + g.z, y2 = g.y + g.w;
            sgt[tid] = make_float4(g.x, g.y, x2, y2);
            float gar = (x2 - g.x) * (y2 - g.y);
            sgq[tid] = make_float2(q * gar, gar);
            if (n == 0) snobj[bb] = nobj[b];
        }
        __syncthreads();

        int abase = sblk*1024 + wv*256;
        float4 A[4]; float aar[4], qa[4]; int orig[4];
        float bx1 = 1e30f, by1 = 1e30f, bx2 = -1e30f, by2 = -1e30f;
        #pragma unroll
        for (int k = 0; k < 4; ++k) {
            int s = abase + k*64 + ln;
            A[k] = sorted[s]; orig[k] = sidx[s];
            aar[k] = (A[k].z - A[k].x) * (A[k].w - A[k].y);
            qa[k]  = q * aar[k];
            bx1 = fminf(bx1, A[k].x); by1 = fminf(by1, A[k].y);
            bx2 = fmaxf(bx2, A[k].z); by2 = fmaxf(by2, A[k].w);
        }
        #pragma unroll
        for (int off = 32; off; off >>= 1) {
            bx1 = fminf(bx1, __shfl_xor(bx1, off, 64));
            by1 = fminf(by1, __shfl_xor(by1, off, 64));
            bx2 = fmaxf(bx2, __shfl_xor(bx2, off, 64));
            by2 = fmaxf(by2, __shfl_xor(by2, off, 64));
        }

        const float2* cls2 = reinterpret_cast<const float2*>(classes);
        for (int bb = 0; bb < 4; ++bb) {
            int b = bg + 4*bb, no = snobj[bb], base = bb*64;
            int cnt[4] = {0,0,0,0};
            for (int n = 0; n < no; ++n) {
                float4 g = sgt[base + n];
                // wave-uniform skip: inter>0 requires box overlap with wave bbox
                if (!(g.x < bx2 && g.z > bx1 && g.y < by2 && g.w > by1)) continue;
                float2 gq = sgq[base + n];
                ull mypk = 0;
                #pragma unroll
                for (int k = 0; k < 4; ++k) {
                    float lx = fmaxf(A[k].x, g.x);
                    float ly = fmaxf(A[k].y, g.y);
                    float rx = fminf(A[k].z, g.z);
                    float ry = fminf(A[k].w, g.w);
                    float w  = fmaxf(rx - lx, 0.f);
                    float h  = fmaxf(ry - ly, 0.f);
                    float inter = w * h;
                    cnt[k] += (inter > qa[k] + gq.x) ? 1 : 0;
                    float sa = aar[k] + gq.y;                     // > 0
                    float r  = inter * __builtin_amdgcn_rcpf(sa); // order only
                    ull pk = ((ull)__float_as_uint(r) << 32)
                           | (ull)(0x7FFFFFFFu - (unsigned)orig[k]);
                    mypk = pk > mypk ? pk : mypk;
                }
                #pragma unroll
                for (int off = 32; off; off >>= 1) {
                    ull o = __shfl_xor(mypk, off, 64);
                    mypk = o > mypk ? o : mypk;
                }
                if (ln == 0) atomicMax(&cells[b*NMAX + n], mypk);
            }
            int any = cnt[0] | cnt[1] | cnt[2] | cnt[3];
            if (__ballot(any != 0)) {
                #pragma unroll
                for (int k = 0; k < 4; ++k) {
                    if (cnt[k] > 0) {
                        float2 cc = cls2[(size_t)b * NANCH + orig[k]];
                        float fg  = focal_f(cc.y);
                        float bgf = focal_f(cc.x);
                        acc += (double)(fg * (1.0f + 10.0f * (float)cnt[k]))
                             - (double)bgf;
                    }
                }
            }
        }
    } else {
        // ---------------- role B: background focal stream ----------------
        int rid = bid >> 1;              // 0..511
        const float4* c4 = reinterpret_cast<const float4*>(classes);
        size_t base = (size_t)rid * 2048 + tid;   // 1,048,576 float4 total
        #pragma unroll
        for (int it = 0; it < 8; ++it) {
            float4 v = c4[base + (size_t)it * 256];
            acc += (double)focal_f(v.x) + (double)focal_f(v.z);
        }
    }

    #pragma unroll
    for (int off = 32; off; off >>= 1) acc += __shfl_xor(acc, off, 64);
    if (ln == 0) sw[wv] = acc;
    __syncthreads();
    if (tid == 0) partials[bid] = sw[0] + sw[1] + sw[2] + sw[3];
}

// ===================== fallback path (proven R10, no parea) ================
#define APT      4
#define ACH      (THREADS*APT)
#define NPAIR    8
#define NB_CNT   ((NANCH/ACH)*NPAIR)     // 1024
#define AC_ANCH  256
#define BPB_A    128
#define MAXB     16
#define NB_ARG   (MAXB*BPB_A)
#define GRID_FB  (NB_CNT+NB_ARG)

__global__ __launch_bounds__(256) void k_setup_fb(
    const int* __restrict__ nobj, ull* __restrict__ cells,
    int* __restrict__ pairs, int* __restrict__ lanepk, int* __restrict__ nbund)
{
    int tid = threadIdx.x;
    for (int i = tid; i < NBATCH*NMAX; i += 256) cells[i] = 0ull;
    for (int i = tid; i < MAXB*NMAX; i += 256) lanepk[i] = -1;
    __syncthreads();
    if (tid) return;
    int ord[NBATCH], key[NBATCH];
    for (int i = 0; i < NBATCH; ++i) { ord[i] = i; key[i] = nobj[i]; }
    for (int i = 1; i < NBATCH; ++i) {
        int k = key[i], o = ord[i], j = i-1;
        while (j >= 0 && key[j] < k) { key[j+1]=key[j]; ord[j+1]=ord[j]; --j; }
        key[j+1] = k; ord[j+1] = o;
    }
    for (int p = 0; p < NPAIR; ++p) { pairs[2*p] = ord[p]; pairs[2*p+1] = ord[NBATCH-1-p]; }
    int rem[MAXB]; int nb = 0;
    for (int i = 0; i < NBATCH; ++i) {
        int n = key[i], f = -1;
        for (int x = 0; x < nb; ++x) if (rem[x] >= n) { f = x; break; }
        if (f < 0) { f = nb++; rem[f] = NMAX; }
        int st = NMAX - rem[f];
        for (int k = 0; k < n; ++k) lanepk[f*NMAX + st + k] = (ord[i] << 8) | k;
        rem[f] -= n;
    }
    *nbund = nb;
}

__global__ __launch_bounds__(THREADS) void k_main_fb(
    const float* __restrict__ thr_p, const float* __restrict__ classes,
    const float* __restrict__ anchors, const float* __restrict__ gt,
    const int* __restrict__ nobj, const int* __restrict__ pairs,
    const int* __restrict__ lanepk, const int* __restrict__ nbund,
    ull* __restrict__ cells, double* __restrict__ partials)
{
    int bid0 = blockIdx.x, tid = threadIdx.x;
    float thr = *thr_p;
    float q   = thr / (1.0f + thr);
    bool is_cnt = (bid0 % 3) == 0;
    int  bid    = is_cnt ? (bid0 / 3) : ((bid0 / 3) * 2 + (bid0 % 3) - 1);

    if (is_cnt) {
        int chunk = bid >> 3, pr = bid & 7;
        int b0 = pairs[2*pr], b1 = pairs[2*pr+1];
        int no0 = nobj[b0], no1 = nobj[b1];
        __shared__ float4 sbox[2*NMAX];
        __shared__ float  sqg[2*NMAX];
        __shared__ double sw[4];
        if (tid < 2*NMAX) {
            int s = tid >> 6, n = tid & 63;
            int b  = s ? b1 : b0;
            int no = s ? no1 : no0;
            float4 g = reinterpret_cast<const float4*>(gt)[b*NMAX + n];
            float x2 = g.x + g.z, y2 = g.y + g.w;
            float4 box = make_float4(g.x, g.y, x2, y2);
            float  qg  = q * ((x2 - g.x) * (y2 - g.y));
            if (n >= no) { box = make_float4(4.f,4.f,4.f,4.f); qg = __builtin_inff(); }
            sbox[tid] = box; sqg[tid] = qg;
        }
        __syncthreads();
        float ax1[APT], ay1[APT], ax2[APT], ay2[APT], qa[APT];
        int abase = chunk * ACH + tid;
        #pragma unroll
        for (int k = 0; k < APT; ++k) {
            float4 v = reinterpret_cast<const float4*>(anchors)[abase + k*THREADS];
            ax1[k]=v.x; ay1[k]=v.y; ax2[k]=v.z; ay2[k]=v.w;
            qa[k] = q * ((v.z - v.x) * (v.w - v.y));
        }
        int wv = tid >> 6, ln = tid & 63;
        double acc = 0.0;
        #pragma unroll
        for (int s = 0; s < 2; ++s) {
            int b = s ? b1 : b0, no = s ? no1 : no0;
            int no4 = (no + 3) & ~3, base = s * NMAX;
            int cnt[APT];
            #pragma unroll
            for (int k = 0; k < APT; ++k) cnt[k] = 0;
            for (int n = 0; n < no4; n += 4) {
                #pragma unroll
                for (int u = 0; u < 4; ++u) {
                    float4 g = sbox[base + n + u];
                    float qg = sqg[base + n + u];
                    #pragma unroll
                    for (int k = 0; k < APT; ++k) {
                        float lx = fmaxf(ax1[k], g.x);
                        float ly = fmaxf(ay1[k], g.y);
                        float rx = fminf(ax2[k], g.z);
                        float ry = fminf(ay2[k], g.w);
                        float w = fmaxf(rx - lx, 0.f), h = fmaxf(ry - ly, 0.f);
                        float inter = w * h;
                        cnt[k] += (inter > qa[k] + qg) ? 1 : 0;
                    }
                }
            }
            const float2* cp = reinterpret_cast<const float2*>(classes) + (size_t)b * NANCH;
            #pragma unroll
            for (int k = 0; k < APT; ++k) {
                float2 c = cp[abase + k*THREADS];
                float p = (cnt[k] > 0) ? c.y : c.x;
                float f = focal_f(p);
                acc += (double)(f * (1.0f + 10.0f * (float)cnt[k]));
            }
        }
        #pragma unroll
        for (int off = 32; off; off >>= 1) acc += __shfl_xor(acc, off, 64);
        if (ln == 0) sw[wv] = acc;
        __syncthreads();
        if (tid == 0) partials[bid] = sw[0] + sw[1] + sw[2] + sw[3];
    } else {
        int bu = bid >> 7, blkc = bid & (BPB_A - 1);
        if (bu >= *nbund) return;
        int wv = tid >> 6, ln = tid & 63;
        int abase = (blkc*4 + wv) * AC_ANCH;
        int lp = lanepk[bu*NMAX + ln];
        bool valid = lp >= 0;
        int gidx = valid ? ((lp >> 8)*NMAX + (lp & 255)) : 0;
        float4 gg = reinterpret_cast<const float4*>(gt)[gidx];
        float gx2 = gg.x + gg.z, gy2 = gg.y + gg.w;
        float gar = (gx2 - gg.x) * (gy2 - gg.y);
        float bn[8], bs[8]; int bj[8];
        #pragma unroll
        for (int u = 0; u < 8; ++u) { bn[u] = -1.f; bs[u] = 1.f; bj[u] = 0; }
        const float4* ap = reinterpret_cast<const float4*>(anchors) + abase;
        for (int j = 0; j < AC_ANCH; j += 8) {
            #pragma unroll
            for (int u = 0; u < 8; ++u) {
                float4 v = ap[j + u];
                float aar = (v.z - v.x) * (v.w - v.y);
                float lx = fmaxf(v.x, gg.x), ly = fmaxf(v.y, gg.y);
                float rx = fminf(v.z, gx2),  ry = fminf(v.w, gy2);
                float w = fmaxf(rx - lx, 0.f), h = fmaxf(ry - ly, 0.f);
                float inter = w * h;
                float sa = aar + gar;
                bool better = inter * bs[u] > bn[u] * sa;
                bn[u] = better ? inter : bn[u];
                bs[u] = better ? sa    : bs[u];
                bj[u] = better ? (j+u) : bj[u];
            }
        }
        if (valid) {
            ull best = 0;
            #pragma unroll
            for (int u = 0; u < 8; ++u) {
                float rr = bn[u] * __builtin_amdgcn_rcpf(bs[u]);
                unsigned aidx = (unsigned)(abase + bj[u]);
                ull pk = ((ull)__float_as_uint(rr) << 32) | (ull)(0x7FFFFFFFu - aidx);
                best = pk > best ? pk : best;
            }
            atomicMax(&cells[(lp >> 8)*NMAX + (lp & 255)], best);
        }
    }
}

// ======================= shared tail (both paths) ==========================
__global__ __launch_bounds__(1024) void k_tail(
    const float* __restrict__ thr_p, const float* __restrict__ classes,
    const float* __restrict__ anchors, const float* __restrict__ gt,
    const int* __restrict__ nobj, const ull* __restrict__ cells,
    const double* __restrict__ partials, float* __restrict__ out)
{
    int tid = threadIdx.x;
    int b = tid >> 6, n = tid & 63;
    float thr = *thr_p;
    float q   = thr / (1.0f + thr);

    __shared__ float4 sbox[NBATCH*NMAX];
    __shared__ float  sqg[NBATCH*NMAX];
    __shared__ int    sidxs[NBATCH*NMAX];
    __shared__ double sdelta[NBATCH];
    __shared__ double sw[16];

    int n_obj = nobj[b];
    {
        float4 g = reinterpret_cast<const float4*>(gt)[b*NMAX + n];
        float x2 = g.x + g.z, y2 = g.y + g.w;
        sbox[tid] = make_float4(g.x, g.y, x2, y2);
        float gar = (x2 - g.x) * (y2 - g.y);
        sqg[tid]  = q * gar;
    }
    __syncthreads();

    int bi = -1; bool need = false;
    float4 av = make_float4(0.f,0.f,0.f,0.f);
    float qa = 0.f;
    if (n < n_obj) {
        ull pkv = cells[tid];
        bi = (int)(0x7FFFFFFFu - (unsigned)(pkv & 0xFFFFFFFFull));
        av = reinterpret_cast<const float4*>(anchors)[bi];
        float aar = (av.z - av.x) * (av.w - av.y);
        qa = q * aar;
        float4 g = sbox[tid];
        float lx = fmaxf(av.x, g.x), ly = fmaxf(av.y, g.y);
        float rx = fminf(av.z, g.z), ry = fminf(av.w, g.w);
        float w = fmaxf(rx - lx, 0.f), h = fmaxf(ry - ly, 0.f);
        float inter = w * h;
        need = !(inter > qa + sqg[tid]);
    }
    sidxs[tid] = need ? bi : -1;
    __syncthreads();

    double delta = 0.0;
    if (need) {
        bool first = true; int extra = 0;
        int base = b * NMAX;
        for (int m = 0; m < NMAX; ++m) {
            if (sidxs[base + m] == bi) { if (m < n) first = false; ++extra; }
        }
        if (first) {
            int count = 0;
            for (int m = 0; m < n_obj; ++m) {
                float4 g = sbox[base + m];
                float lx = fmaxf(av.x, g.x), ly = fmaxf(av.y, g.y);
                float rx = fminf(av.z, g.z), ry = fminf(av.w, g.w);
                float w = fmaxf(rx - lx, 0.f), h = fmaxf(ry - ly, 0.f);
                float inter = w * h;
                count += (inter > qa + sqg[base + m]) ? 1 : 0;
            }
            float2 c = reinterpret_cast<const float2*>(classes)[(size_t)b * NANCH + bi];
            float po = (count > 0) ? c.y : c.x;
            float fo = focal_f(po);
            float oldc = fo * (1.0f + 10.0f * (float)count);
            int cn = count + extra;
            float pn = (cn > 0) ? c.y : c.x;
            float fn = focal_f(pn);
            float newc = fn * (1.0f + 10.0f * (float)cn);
            delta = (double)newc - (double)oldc;
        }
    }
    #pragma unroll
    for (int off = 32; off; off >>= 1) delta += __shfl_xor(delta, off, 64);
    if (n == 0) sdelta[b] = delta;
    __syncthreads();

    double v = partials[tid];
    if (tid < NBATCH) v += sdelta[tid];
    #pragma unroll
    for (int off = 32; off; off >>= 1) v += __shfl_xor(v, off, 64);
    if ((tid & 63) == 0) sw[tid >> 6] = v;
    __syncthreads();
    if (tid == 0) {
        double tot = 0.0;
        #pragma unroll
        for (int i = 0; i < 16; ++i) tot += sw[i];
        double cls = tot * (0.01 / 16.0);
        out[0] = (float)cls;
        out[1] = (float)cls;
        out[2] = 0.0f;
    }
}

extern "C" void kernel_launch(void* const* d_in, const int* in_sizes, int n_in,
                              void* d_out, int out_size, void* d_ws, size_t ws_size,
                              hipStream_t stream) {
    const float* thr     = (const float*)d_in[0];
    const float* classes = (const float*)d_in[1];
    const float* anchors = (const float*)d_in[2];
    const float* gt      = (const float*)d_in[3];
    const int*   nobj    = (const int*)d_in[4];
    float* out = (float*)d_out;

    char* ws = (char*)d_ws;
    ull*    cells    = (ull*)(ws + 0);
    double* partials = (double*)(ws + OFF_PART);

    if (ws_size >= (size_t)WS_NEED) {
        int*    CH     = (int*)(ws + OFF_CH);
        int*    cellid = (int*)(ws + OFF_CID);
        float4* sorted = (float4*)(ws + OFF_SRT);
        int*    sidx   = (int*)(ws + OFF_SIX);
        k_hist<<<256, 256, 0, stream>>>(anchors, cellid, CH);
        k_scan<<<1, 256, 0, stream>>>(CH, cells);
        k_scatter<<<256, 256, 0, stream>>>(anchors, cellid, CH, sorted, sidx);
        k_main_s<<<1024, THREADS, 0, stream>>>(thr, classes, sorted, sidx,
                                               gt, nobj, cells, partials);
    } else {
        int* pairs  = (int*)(ws + OFF_PAIRS);
        int* lanepk = (int*)(ws + OFF_LANE);
        int* nbund  = (int*)(ws + OFF_NB);
        k_setup_fb<<<1, 256, 0, stream>>>(nobj, cells, pairs, lanepk, nbund);
        k_main_fb<<<GRID_FB, THREADS, 0, stream>>>(thr, classes, anchors, gt, nobj,
                                                   pairs, lanepk, nbund, cells, partials);
    }
    k_tail<<<1, 1024, 0, stream>>>(thr, classes, anchors, gt, nobj, cells, partials, out);
}